// Round 1
// baseline (234.018 us; speedup 1.0000x reference)
//
#include <hip/hip_runtime.h>
#include <hip/hip_bf16.h>

#define D64 64

__device__ inline float lane_bcast(float v, int l) {
    return __uint_as_float(__builtin_amdgcn_readlane(__float_as_uint(v), l));
}

// out[r][a] = (relu?) sum_d in[r][d] * W[a][d]   (W row-major [64][64])
template<bool RELU>
__global__ void rowmm_kernel(const float* __restrict__ in, const float* __restrict__ W,
                             float* __restrict__ out, int nrows) {
    __shared__ float WT[D64 * D64];  // WT[d][a] = W[a][d]
    int tid = threadIdx.x;
    for (int i = tid; i < D64 * D64; i += blockDim.x) {
        WT[(i & 63) * D64 + (i >> 6)] = W[i];
    }
    __syncthreads();
    int lane = tid & 63;
    int wid = (blockIdx.x * blockDim.x + tid) >> 6;
    int nw = (gridDim.x * blockDim.x) >> 6;
    for (int r = wid; r < nrows; r += nw) {
        float v = in[r * D64 + lane];
        float acc = 0.f;
#pragma unroll
        for (int d = 0; d < D64; ++d) {
            acc = fmaf(lane_bcast(v, d), WT[d * D64 + lane], acc);
        }
        out[r * D64 + lane] = RELU ? fmaxf(acc, 0.f) : acc;
    }
}

// Per-relation tables: hrmap[r] = emb[mapping[r]]; hrW[r] = hrmap[r] @ Wr.T
// Per-query: qr_attn[q] = emb[mapping[q_rel[q]]] @ Wqr.T + Wqr_b
__global__ void prep_kernel(const float* __restrict__ emb, const int* __restrict__ mapping,
                            const int* __restrict__ q_rel,
                            const float* __restrict__ Wr, const float* __restrict__ Wqr,
                            const float* __restrict__ Wqr_b,
                            float* __restrict__ hrmap, float* __restrict__ hrW,
                            float* __restrict__ qr_attn, int nrel, int nq) {
    int b = blockIdx.x;
    int lane = threadIdx.x;
    if (b < nrel) {
        int m = mapping[b];
        float v = emb[m * D64 + lane];
        hrmap[b * D64 + lane] = v;
        float acc = 0.f;
#pragma unroll
        for (int d = 0; d < D64; ++d)
            acc = fmaf(lane_bcast(v, d), Wr[lane * D64 + d], acc);
        hrW[b * D64 + lane] = acc;
    } else {
        int q = b - nrel;
        if (q < nq) {
            int m = mapping[q_rel[q]];
            float v = emb[m * D64 + lane];
            float acc = Wqr_b[lane];
#pragma unroll
            for (int d = 0; d < D64; ++d)
                acc = fmaf(lane_bcast(v, d), Wqr[lane * D64 + d], acc);
            qr_attn[q * D64 + lane] = acc;
        }
    }
}

// One wave per edge (grid-stride): alpha + message + atomic segment-sum
__global__ void edge_kernel(const int* __restrict__ edges, const int* __restrict__ r_idx,
                            const float* __restrict__ hidden, const float* __restrict__ hsW,
                            const float* __restrict__ hrmap, const float* __restrict__ hrW,
                            const float* __restrict__ qr_attn,
                            const float* __restrict__ walpha_w, const float* __restrict__ walpha_b,
                            float* __restrict__ agg, int E) {
    int lane = threadIdx.x & 63;
    int wid = (blockIdx.x * blockDim.x + threadIdx.x) >> 6;
    int nw = (gridDim.x * blockDim.x) >> 6;
    float wa = walpha_w[lane];
    float wb = walpha_b[0];
    for (int e = wid; e < E; e += nw) {
        int sub = edges[e * 3 + 0];
        int rel = edges[e * 3 + 1];
        int obj = edges[e * 3 + 2];
        int ri = r_idx[e];
        float pre = hsW[sub * D64 + lane] + hrW[rel * D64 + lane] + qr_attn[ri * D64 + lane];
        float x = fmaxf(pre, 0.f) * wa;
#pragma unroll
        for (int off = 32; off; off >>= 1) x += __shfl_xor(x, off, 64);
        float alpha = 1.f / (1.f + __expf(-(x + wb)));
        float msg = alpha * hidden[sub * D64 + lane] * hrmap[rel * D64 + lane];
        atomicAdd(&agg[obj * D64 + lane], msg);
    }
}

extern "C" void kernel_launch(void* const* d_in, const int* in_sizes, int n_in,
                              void* d_out, int out_size, void* d_ws, size_t ws_size,
                              hipStream_t stream) {
    const float* hidden   = (const float*)d_in[0];
    const int*   edges    = (const int*)d_in[1];
    const float* emb_rel  = (const float*)d_in[2];
    const int*   mapping  = (const int*)d_in[3];
    const int*   q_rel    = (const int*)d_in[4];
    const int*   r_idx    = (const int*)d_in[5];
    // d_in[6] = n_node scalar (device); use in_sizes instead
    const float* Ws_w     = (const float*)d_in[7];
    const float* Wr_w     = (const float*)d_in[8];
    const float* Wqr_w    = (const float*)d_in[9];
    const float* Wqr_b    = (const float*)d_in[10];
    const float* walpha_w = (const float*)d_in[11];
    const float* walpha_b = (const float*)d_in[12];
    const float* Wh_w     = (const float*)d_in[13];
    float* out = (float*)d_out;

    int NN   = in_sizes[0] / D64;   // 50000
    int E    = in_sizes[5];         // 800000
    int NREL = in_sizes[3];         // 475
    int NQ   = in_sizes[4];         // 32

    // workspace layout (floats)
    char* ws = (char*)d_ws;
    float* hsW     = (float*)ws;                                   // NN*64
    float* agg     = hsW + (size_t)NN * D64;                       // NN*64
    float* hrmap   = agg + (size_t)NN * D64;                       // NREL*64
    float* hrW     = hrmap + (size_t)NREL * D64;                   // NREL*64
    float* qr_attn = hrW + (size_t)NREL * D64;                     // NQ*64

    // 1) relation/query tables
    prep_kernel<<<NREL + NQ, 64, 0, stream>>>(emb_rel, mapping, q_rel, Wr_w, Wqr_w, Wqr_b,
                                              hrmap, hrW, qr_attn, NREL, NQ);
    // 2) hsW = hidden @ Ws.T
    rowmm_kernel<false><<<1024, 256, 0, stream>>>(hidden, Ws_w, hsW, NN);
    // 3) zero agg, then edge kernel
    hipMemsetAsync(agg, 0, (size_t)NN * D64 * sizeof(float), stream);
    edge_kernel<<<2048, 256, 0, stream>>>(edges, r_idx, hidden, hsW, hrmap, hrW, qr_attn,
                                          walpha_w, walpha_b, agg, E);
    // 4) out = relu(agg @ Wh.T)
    rowmm_kernel<true><<<1024, 256, 0, stream>>>(agg, Wh_w, out, NN);
}

// Round 2
// 230.395 us; speedup vs baseline: 1.0157x; 1.0157x over previous
//
#include <hip/hip_runtime.h>
#include <hip/hip_bf16.h>

#define D64 64

__device__ inline float lane_bcast(float v, int l) {
    return __uint_as_float(__builtin_amdgcn_readlane(__float_as_uint(v), l));
}

// out[r][a] = (relu?) sum_d in[r][d] * W[a][d]   (W row-major [64][64])
// in/out intentionally NOT __restrict__ (final call runs in place on d_out).
template<bool RELU>
__global__ void rowmm_kernel(const float* in, const float* __restrict__ W,
                             float* out, int nrows) {
    __shared__ float WT[D64 * D64];  // WT[d][a] = W[a][d]
    int tid = threadIdx.x;
    for (int i = tid; i < D64 * D64; i += blockDim.x)
        WT[(i & 63) * D64 + (i >> 6)] = W[i];
    __syncthreads();
    int lane = tid & 63;
    int wid = (blockIdx.x * blockDim.x + tid) >> 6;
    int nw = (gridDim.x * blockDim.x) >> 6;
    for (int r = wid; r < nrows; r += nw) {
        float v = in[r * D64 + lane];
        float acc = 0.f;
#pragma unroll
        for (int d = 0; d < D64; ++d)
            acc = fmaf(lane_bcast(v, d), WT[d * D64 + lane], acc);
        if (RELU) acc = fmaxf(acc, 0.f);
        out[r * D64 + lane] = acc;
    }
}

// Per-relation tables: hrmap[r] = emb[mapping[r]]; hrW[r] = hrmap[r] @ Wr.T
// Per-query: qr_attn[q] = emb[mapping[q_rel[q]]] @ Wqr.T + Wqr_b
__global__ void prep_kernel(const float* __restrict__ emb, const int* __restrict__ mapping,
                            const int* __restrict__ q_rel,
                            const float* __restrict__ Wr, const float* __restrict__ Wqr,
                            const float* __restrict__ Wqr_b,
                            float* __restrict__ hrmap, float* __restrict__ hrW,
                            float* __restrict__ qr_attn, int nrel, int nq) {
    int b = blockIdx.x;
    int lane = threadIdx.x;
    if (b < nrel) {
        int m = mapping[b];
        float v = emb[m * D64 + lane];
        hrmap[b * D64 + lane] = v;
        float acc = 0.f;
#pragma unroll
        for (int d = 0; d < D64; ++d)
            acc = fmaf(lane_bcast(v, d), Wr[lane * D64 + d], acc);
        hrW[b * D64 + lane] = acc;
    } else {
        int q = b - nrel;
        if (q < nq) {
            int m = mapping[q_rel[q]];
            float v = emb[m * D64 + lane];
            float acc = Wqr_b[lane];
#pragma unroll
            for (int d = 0; d < D64; ++d)
                acc = fmaf(lane_bcast(v, d), Wqr[lane * D64 + d], acc);
            qr_attn[q * D64 + lane] = acc;
        }
    }
}

__global__ void hist_kernel(const int* __restrict__ edges, int* __restrict__ counts, int E) {
    int i = blockIdx.x * blockDim.x + threadIdx.x;
    if (i < E) atomicAdd(&counts[edges[i * 3 + 2]], 1);
}

// Block-level exclusive scan: 1024 elements/block (256 thr x 4). Writes local
// exclusive results to offs and the block total to partials[blockIdx].
__global__ void scan1_kernel(const int* __restrict__ counts, int* __restrict__ offs,
                             int* __restrict__ partials, int n) {
    __shared__ int tsum[256];
    int t = threadIdx.x;
    int base = blockIdx.x * 1024 + t * 4;
    int v[4];
    int s = 0;
#pragma unroll
    for (int i = 0; i < 4; ++i) {
        int idx = base + i;
        int c = (idx < n) ? counts[idx] : 0;
        v[i] = s;          // exclusive within thread
        s += c;
    }
    tsum[t] = s;
    __syncthreads();
    for (int off = 1; off < 256; off <<= 1) {
        int y = (t >= off) ? tsum[t - off] : 0;
        __syncthreads();
        tsum[t] += y;
        __syncthreads();
    }
    int incl = tsum[t];
    int thread_prefix = incl - s;
    if (t == 255) partials[blockIdx.x] = incl;
#pragma unroll
    for (int i = 0; i < 4; ++i) {
        int idx = base + i;
        if (idx < n) offs[idx] = thread_prefix + v[i];
    }
}

// Exclusive scan of block partials (nb <= 64), one wave.
__global__ void scan2_kernel(int* partials, int nb) {
    int t = threadIdx.x;
    int own = (t < nb) ? partials[t] : 0;
    int v = own;
    for (int off = 1; off < 64; off <<= 1) {
        int y = __shfl_up(v, off, 64);
        if (t >= off) v += y;
    }
    if (t < nb) partials[t] = v - own;
}

__global__ void scan3_kernel(int* __restrict__ offs, const int* __restrict__ partials, int n) {
    int base = blockIdx.x * 1024 + threadIdx.x;
    int add = partials[blockIdx.x];
#pragma unroll
    for (int i = 0; i < 4; ++i) {
        int idx = base + i * 256;
        if (idx < n) offs[idx] += add;
    }
}

// Scatter packed records by destination; mutates offs so that afterwards
// offs[n] == inclusive segment end of node n.
__global__ void scatter_kernel(const int* __restrict__ edges, const int* __restrict__ r_idx,
                               int* __restrict__ offs, int2* __restrict__ rec, int E) {
    int i = blockIdx.x * blockDim.x + threadIdx.x;
    if (i < E) {
        int sub = edges[i * 3 + 0];
        int rel = edges[i * 3 + 1];
        int obj = edges[i * 3 + 2];
        int ri  = r_idx[i];
        int slot = atomicAdd(&offs[obj], 1);
        rec[slot] = make_int2(sub, (rel << 5) | ri);
    }
}

// One wave per destination node: register accumulation, single store.
__global__ void agg_kernel(const int2* __restrict__ rec, const int* __restrict__ endoff,
                           const float* __restrict__ hidden, const float* __restrict__ hsW,
                           const float* __restrict__ hrmap, const float* __restrict__ hrW,
                           const float* __restrict__ qr_attn,
                           const float* __restrict__ walpha_w, const float* __restrict__ walpha_b,
                           float* __restrict__ aggout, int NN) {
    int lane = threadIdx.x & 63;
    int wid = (blockIdx.x * blockDim.x + threadIdx.x) >> 6;
    if (wid >= NN) return;
    int n = wid;
    float wa = walpha_w[lane];
    float wb = walpha_b[0];
    int start = (n == 0) ? 0 : endoff[n - 1];
    int end = endoff[n];
    float acc = 0.f;
    int i = start;
    for (; i + 1 < end; i += 2) {
        int2 r0 = rec[i], r1 = rec[i + 1];
        int s0 = r0.x, e0 = r0.y >> 5, q0 = r0.y & 31;
        int s1 = r1.x, e1 = r1.y >> 5, q1 = r1.y & 31;
        float pre0 = hsW[s0 * D64 + lane] + hrW[e0 * D64 + lane] + qr_attn[q0 * D64 + lane];
        float pre1 = hsW[s1 * D64 + lane] + hrW[e1 * D64 + lane] + qr_attn[q1 * D64 + lane];
        float x0 = fmaxf(pre0, 0.f) * wa;
        float x1 = fmaxf(pre1, 0.f) * wa;
#pragma unroll
        for (int off = 32; off; off >>= 1) {
            x0 += __shfl_xor(x0, off, 64);
            x1 += __shfl_xor(x1, off, 64);
        }
        float a0 = 1.f / (1.f + __expf(-(x0 + wb)));
        float a1 = 1.f / (1.f + __expf(-(x1 + wb)));
        acc = fmaf(a0 * hidden[s0 * D64 + lane], hrmap[e0 * D64 + lane], acc);
        acc = fmaf(a1 * hidden[s1 * D64 + lane], hrmap[e1 * D64 + lane], acc);
    }
    if (i < end) {
        int2 r0 = rec[i];
        int s0 = r0.x, e0 = r0.y >> 5, q0 = r0.y & 31;
        float pre0 = hsW[s0 * D64 + lane] + hrW[e0 * D64 + lane] + qr_attn[q0 * D64 + lane];
        float x0 = fmaxf(pre0, 0.f) * wa;
#pragma unroll
        for (int off = 32; off; off >>= 1) x0 += __shfl_xor(x0, off, 64);
        float a0 = 1.f / (1.f + __expf(-(x0 + wb)));
        acc = fmaf(a0 * hidden[s0 * D64 + lane], hrmap[e0 * D64 + lane], acc);
    }
    aggout[n * D64 + lane] = acc;
}

extern "C" void kernel_launch(void* const* d_in, const int* in_sizes, int n_in,
                              void* d_out, int out_size, void* d_ws, size_t ws_size,
                              hipStream_t stream) {
    const float* hidden   = (const float*)d_in[0];
    const int*   edges    = (const int*)d_in[1];
    const float* emb_rel  = (const float*)d_in[2];
    const int*   mapping  = (const int*)d_in[3];
    const int*   q_rel    = (const int*)d_in[4];
    const int*   r_idx    = (const int*)d_in[5];
    const float* Ws_w     = (const float*)d_in[7];
    const float* Wr_w     = (const float*)d_in[8];
    const float* Wqr_w    = (const float*)d_in[9];
    const float* Wqr_b    = (const float*)d_in[10];
    const float* walpha_w = (const float*)d_in[11];
    const float* walpha_b = (const float*)d_in[12];
    const float* Wh_w     = (const float*)d_in[13];
    float* out = (float*)d_out;

    int NN   = in_sizes[0] / D64;   // 50000
    int E    = in_sizes[5];         // 800000
    int NREL = in_sizes[3];         // 475
    int NQ   = in_sizes[4];         // 32

    // workspace layout
    char* ws = (char*)d_ws;
    size_t off = 0;
    float* hsW = (float*)(ws + off);      off += (size_t)NN * D64 * sizeof(float);   // 12.8 MB
    int2*  rec = (int2*)(ws + off);       off += (size_t)E * sizeof(int2);           // 6.4 MB
    int* counts = (int*)(ws + off);       off += (size_t)NN * sizeof(int);           // 0.2 MB
    int* offs   = (int*)(ws + off);       off += (size_t)NN * sizeof(int);           // 0.2 MB
    int* partials = (int*)(ws + off);     off += 64 * sizeof(int);
    float* hrmap = (float*)(ws + off);    off += (size_t)NREL * D64 * sizeof(float);
    float* hrW   = (float*)(ws + off);    off += (size_t)NREL * D64 * sizeof(float);
    float* qr_attn = (float*)(ws + off);  off += (size_t)NQ * D64 * sizeof(float);

    int NB = (NN + 1023) / 1024;  // scan blocks (49)

    hipMemsetAsync(counts, 0, (size_t)NN * sizeof(int), stream);
    prep_kernel<<<NREL + NQ, 64, 0, stream>>>(emb_rel, mapping, q_rel, Wr_w, Wqr_w, Wqr_b,
                                              hrmap, hrW, qr_attn, NREL, NQ);
    rowmm_kernel<false><<<1024, 256, 0, stream>>>(hidden, Ws_w, hsW, NN);
    hist_kernel<<<(E + 255) / 256, 256, 0, stream>>>(edges, counts, E);
    scan1_kernel<<<NB, 256, 0, stream>>>(counts, offs, partials, NN);
    scan2_kernel<<<1, 64, 0, stream>>>(partials, NB);
    scan3_kernel<<<NB, 256, 0, stream>>>(offs, partials, NN);
    scatter_kernel<<<(E + 255) / 256, 256, 0, stream>>>(edges, r_idx, offs, rec, E);
    // aggregate straight into d_out, then apply Wh in place
    agg_kernel<<<(NN * 64 + 255) / 256, 256, 0, stream>>>(rec, offs, hidden, hsW, hrmap, hrW,
                                                          qr_attn, walpha_w, walpha_b, out, NN);
    rowmm_kernel<true><<<1024, 256, 0, stream>>>(out, Wh_w, out, NN);
}